// Round 14
// baseline (205.850 us; speedup 1.0000x reference)
//
#include <hip/hip_runtime.h>
#include <hip/hip_bf16.h>

// AdaptiveScaledDotProductAttention (MI355X / gfx950)
// B=8, NQ=NK=1024, D_MODEL=1024, H=8, D_K=D_V=128
// Pipeline: bf16 pre-convert (non-temporal fp32 reads so bf16 outputs stay
// L3-resident for proj) -> fused 4x projection GEMM (128x128, BK=64,
// global_load_lds + XOR-swizzled LDS; V transposed with packed 8B stores)
// -> flash attention with sentinel (32x32x16 MFMA, 8 waves x 32 q-rows,
// defer-max, setprio, XCD-clustered) -> out GEMM (clustered map).
//
// Session ledger (rounds 1-13): 13 variants tested, 1 win + this probe.
//   - 256x256 8-phase counted-vmcnt schedules (x3): MfmaUtil 20-22 vs 30+.
//   - L2 XCD-clustering of proj blocks (x2): FETCH down but dur +28%
//     (cold-A latency-bound; correlated misses lengthen the vmcnt drain).
//   - fp32-A fused convert: cold-miss exposure inside K-loop, -110%.
//   - 32x32x16 MFMA in GEMM cores: 8.4M LDS bank conflicts, -11%.
//   - attn 2-block split: neutral. out_gemm decorrelated map: -4us.
// WIN (r9, confirmed r10/r12): V^T packed 8B stores: WRITE 85->66MB,
// FETCH 77->65.7MB, 215.4->197.6us.
// r14 probe (r13 fixed for compile: nontemporal builtin needs
// ext_vector_type, not HIP_vector_type): proj FETCH=65.7MB shows its A
// (bf16, written by cvt moments earlier) is re-fetched from HBM -- cvt's
// 128MB of dead fp32 reads evict it from L3. nt-loads on the fp32 side
// keep L3 for the bf16 outputs.

typedef __attribute__((ext_vector_type(8))) short s16x8;
typedef __attribute__((ext_vector_type(4))) short s16x4;
typedef __attribute__((ext_vector_type(4))) float f32x4;
typedef __attribute__((ext_vector_type(16))) float f32x16;
typedef __attribute__((ext_vector_type(4))) unsigned int u32x4;

#define DEVI static __device__ __forceinline__

constexpr int BATCH = 8;
constexpr int SEQ   = 1024;
constexpr int NH    = 8;
constexpr int DH    = 128;
constexpr int DM    = 1024;

DEVI short bf16r(float f) {
  __hip_bfloat16 h = __float2bfloat16(f);
  return *reinterpret_cast<short*>(&h);
}
DEVI float bf2f(short s) {
  __hip_bfloat16 h;
  *reinterpret_cast<short*>(&h) = s;
  return __bfloat162float(h);
}
DEVI s16x8 cvt8(const float4& a, const float4& b) {
  s16x8 r;
  r[0] = bf16r(a.x); r[1] = bf16r(a.y); r[2] = bf16r(a.z); r[3] = bf16r(a.w);
  r[4] = bf16r(b.x); r[5] = bf16r(b.y); r[6] = bf16r(b.z); r[7] = bf16r(b.w);
  return r;
}
DEVI s16x8 cvt8v(f32x4 a, f32x4 b) {
  s16x8 r;
  r[0] = bf16r(a[0]); r[1] = bf16r(a[1]); r[2] = bf16r(a[2]); r[3] = bf16r(a[3]);
  r[4] = bf16r(b[0]); r[5] = bf16r(b[1]); r[6] = bf16r(b[2]); r[7] = bf16r(b[3]);
  return r;
}
DEVI unsigned int pack2bf(float a, float b) {
  return (unsigned int)(unsigned short)bf16r(a) |
         ((unsigned int)(unsigned short)bf16r(b) << 16);
}

#define GLOAD16(g, l)                                                        \
  __builtin_amdgcn_global_load_lds(                                          \
      (const __attribute__((address_space(1))) unsigned int*)(g),            \
      (__attribute__((address_space(3))) unsigned int*)(l), 16, 0, 0)

DEVI f32x4 mfma(s16x8 a, s16x8 b, f32x4 c) {
  return __builtin_amdgcn_mfma_f32_16x16x32_bf16(a, b, c, 0, 0, 0);
}
DEVI f32x16 mfma32(s16x8 a, s16x8 b, f32x16 c) {
  return __builtin_amdgcn_mfma_f32_32x32x16_bf16(a, b, c, 0, 0, 0);
}

// ---------------- fp32 -> bf16 convert, all 9 tensors, one launch ----------
// fp32 source reads are NON-TEMPORAL (dead after conversion) so the L3
// retains the bf16 outputs that proj/attn re-read instead.
__global__ __launch_bounds__(256)
void cvt_all(const float* __restrict__ a0, const float* __restrict__ a1,
             const float* __restrict__ a2, const float* __restrict__ a3,
             const float* __restrict__ w0, const float* __restrict__ w1,
             const float* __restrict__ w2, const float* __restrict__ w3,
             const float* __restrict__ w4,
             short* __restrict__ d0, short* __restrict__ d1,
             short* __restrict__ d2, short* __restrict__ d3,
             short* __restrict__ e0, short* __restrict__ e1,
             short* __restrict__ e2, short* __restrict__ e3,
             short* __restrict__ e4) {
  const float* s; short* d; int idx;
  int bid = blockIdx.x;
  if (bid < 16384) {
    int which = bid >> 12; idx = bid & 4095;
    switch (which) {
      case 0: s = a0; d = d0; break;
      case 1: s = a1; d = d1; break;
      case 2: s = a2; d = d2; break;
      default: s = a3; d = d3; break;
    }
  } else {
    int r = bid - 16384;
    int which = r >> 9; idx = r & 511;
    switch (which) {
      case 0: s = w0; d = e0; break;
      case 1: s = w1; d = e1; break;
      case 2: s = w2; d = e2; break;
      case 3: s = w3; d = e3; break;
      default: s = w4; d = e4; break;
    }
  }
  size_t i = ((size_t)idx * 256 + threadIdx.x) * 8;
  f32x4 a = __builtin_nontemporal_load((const f32x4*)(s + i));
  f32x4 b = __builtin_nontemporal_load((const f32x4*)(s + i + 4));
  *(s16x8*)(d + i) = cvt8v(a, b);
}

// ---------------- GEMM core (128x128 tile, BK=64, swizzled LDS) ------------
DEVI void gemm_core(const short* __restrict__ A, const short* __restrict__ W,
                    short* Alds, short* Blds, int m0, int n0,
                    f32x4 (&acc)[4][4]) {
  const int tid = threadIdx.x, lane = tid & 63, wid = tid >> 6;
  const int wm = wid >> 1, wn = wid & 1, lr = lane & 15, lg = lane >> 4;
  const int srow = wid * 32 + (lane >> 3);
  const int scb  = (lane & 7) * 16;

  for (int k0 = 0; k0 < DM; k0 += 64) {
    if (k0) __syncthreads();
#pragma unroll
    for (int t = 0; t < 4; t++) {
      int row = srow + t * 8;
      int cbs = scb ^ ((row & 7) << 4);
      GLOAD16((const char*)A + ((size_t)(m0 + row) * DM + k0) * 2 + cbs,
              (char*)Alds + wid * 4096 + t * 1024);
      GLOAD16((const char*)W + ((size_t)(n0 + row) * DM + k0) * 2 + cbs,
              (char*)Blds + wid * 4096 + t * 1024);
    }
    __syncthreads();
#pragma unroll
    for (int kk = 0; kk < 2; kk++) {
      s16x8 af[4], bf[4];
#pragma unroll
      for (int i = 0; i < 4; i++) {
        int row = wm * 64 + i * 16 + lr;
        af[i] = *(const s16x8*)((const char*)Alds + row * 128 +
                                ((kk * 64 + lg * 16) ^ ((row & 7) << 4)));
      }
#pragma unroll
      for (int j = 0; j < 4; j++) {
        int row = wn * 64 + j * 16 + lr;
        bf[j] = *(const s16x8*)((const char*)Blds + row * 128 +
                                ((kk * 64 + lg * 16) ^ ((row & 7) << 4)));
      }
#pragma unroll
      for (int i = 0; i < 4; i++)
#pragma unroll
        for (int j = 0; j < 4; j++)
          acc[i][j] = mfma(af[i], bf[j], acc[i][j]);
    }
  }
}

// Fused 4-way projection GEMM. z: 0=Q 1=K 2=V(writes V^T) 3=S
__global__ __launch_bounds__(256)
void proj_gemm(const short* __restrict__ qa, const short* __restrict__ ka,
               const short* __restrict__ va, const short* __restrict__ sa,
               const short* __restrict__ wq, const short* __restrict__ wk,
               const short* __restrict__ wv, const short* __restrict__ wsn,
               const float* __restrict__ bq, const float* __restrict__ bk,
               const float* __restrict__ bv, const float* __restrict__ bsn,
               short* __restrict__ Qo, short* __restrict__ Ko,
               short* __restrict__ Vo, short* __restrict__ So) {
  __shared__ short Alds[128 * 64];
  __shared__ short Blds[128 * 64];
  const int z = blockIdx.z;
  const short* A; const short* W; const float* bias; short* C;
  switch (z) {
    case 0: A = qa; W = wq;  bias = bq;  C = Qo; break;
    case 1: A = ka; W = wk;  bias = bk;  C = Ko; break;
    case 2: A = va; W = wv;  bias = bv;  C = Vo; break;
    default: A = sa; W = wsn; bias = bsn; C = So; break;
  }
  const int m0 = blockIdx.x * 128, n0 = blockIdx.y * 128;
  f32x4 acc[4][4] = {};
  gemm_core(A, W, Alds, Blds, m0, n0, acc);

  const int lane = threadIdx.x & 63, wid = threadIdx.x >> 6;
  const int wm = wid >> 1, wn = wid & 1, lr = lane & 15, lg = lane >> 4;
  if (z == 2) {
    // V^T: acc[i][j][0..3] are sq-consecutive -> one 8B packed store each
    // (was 4x 2B at 2KB stride; removes partial-line RMW amplification).
#pragma unroll
    for (int i = 0; i < 4; i++) {
      int mb = m0 + wm * 64 + i * 16 + lg * 4;   // r=0 row
      int bb = mb >> 10, sqb = mb & 1023;        // sqb multiple of 4 -> 8B aligned
#pragma unroll
      for (int j = 0; j < 4; j++) {
        int n = n0 + wn * 64 + j * 16 + lr;
        int hh = n >> 7, d = n & 127;
        float bsv = bias[n];
        s16x4 pk;
#pragma unroll
        for (int r = 0; r < 4; r++) pk[r] = bf16r(acc[i][j][r] + bsv);
        *(s16x4*)(&C[((size_t)(bb * NH + hh) * DH + d) * SEQ + sqb]) = pk;
      }
    }
  } else {
#pragma unroll
    for (int i = 0; i < 4; i++) {
#pragma unroll
      for (int r = 0; r < 4; r++) {
        int m = m0 + wm * 64 + i * 16 + lg * 4 + r;
        int bb = m >> 10, sq = m & 1023;
#pragma unroll
        for (int j = 0; j < 4; j++) {
          int n = n0 + wn * 64 + j * 16 + lr;
          float v = acc[i][j][r] + bias[n];
          int hh = n >> 7, d = n & 127;
          C[((size_t)(bb * NH + hh) * SEQ + sq) * DH + d] = bf16r(v);
        }
      }
    }
  }
}

// Output GEMM: att(bf16 [8192][1024]) @ Wo^T + bo -> fp32 [8192][1024]
// Clustered map kept: A (att) is L3-warm so L2 weight-sharing is pure
// profit here (r11 decorrelation experiment: -4us).
__global__ __launch_bounds__(256)
void out_gemm(const short* __restrict__ A, const short* __restrict__ W,
              const float* __restrict__ bias, float* __restrict__ C) {
  __shared__ short Alds[128 * 64];
  __shared__ short Blds[128 * 64];
  const int bid = blockIdx.x;
  const int wg = (bid & 7) * 64 + (bid >> 3);
  const int m0 = (wg >> 3) * 128, n0 = (wg & 7) * 128;
  f32x4 acc[4][4] = {};
  gemm_core(A, W, Alds, Blds, m0, n0, acc);

  const int lane = threadIdx.x & 63, wid = threadIdx.x >> 6;
  const int wm = wid >> 1, wn = wid & 1, lr = lane & 15, lg = lane >> 4;
#pragma unroll
  for (int i = 0; i < 4; i++)
#pragma unroll
    for (int r = 0; r < 4; r++) {
      int m = m0 + wm * 64 + i * 16 + lg * 4 + r;
#pragma unroll
      for (int j = 0; j < 4; j++) {
        int n = n0 + wn * 64 + j * 16 + lr;
        C[(size_t)m * DM + n] = acc[i][j][r] + bias[n];
      }
    }
}

// ---------------- flash attention with sentinel (32x32x16 MFMA) ------------
// Q,K,S: bf16 [b][h][seq][128]; Vt: bf16 [b][h][128][seq]; att: [b][seq][h*128]
// 8 waves x 32 q-rows = 256 q/block sharing one 64KB K/V double-buffer.
DEVI void stage_kv(const char* Kg, const char* Vg, int k0n,
                   short* Kd, short* Vd, int tid, int wave) {
  const int krow_l = tid >> 4, kslot = tid & 15;   // 512 thr: rows 0..31
  const int vrow_l = tid >> 3, vslot = tid & 7;    // rows 0..63
#pragma unroll
  for (int ln = 0; ln < 2; ln++) {
    int kr = ln * 32 + krow_l;
    int ss = kslot ^ (((kr & 7) << 1) ^ ((kr >> 3) & 3));
    GLOAD16(Kg + (size_t)(k0n + kr) * 256 + ss * 16,
            (char*)Kd + ln * 8192 + wave * 1024);
  }
#pragma unroll
  for (int ln = 0; ln < 2; ln++) {
    int dr = ln * 64 + vrow_l;
    int ss = vslot ^ ((dr & 7) ^ ((dr >> 3) & 3));
    GLOAD16(Vg + (size_t)dr * 2048 + (size_t)k0n * 2 + ss * 16,
            (char*)Vd + ln * 8192 + wave * 1024);
  }
}

__global__ __launch_bounds__(512, 2)
void attn_kernel(const short* __restrict__ Qb, const short* __restrict__ Kb,
                 const short* __restrict__ Vtb, const short* __restrict__ Sb,
                 short* __restrict__ att) {
  __shared__ short Klds[2][64 * 128];    // [k][128], 256B rows, 2x16KB
  __shared__ short Vtlds[2][128 * 64];   // [d][64], 128B rows, 2x16KB

  const int tid = threadIdx.x, lane = tid & 63, wave = tid >> 6;  // 0..7
  const int l31 = lane & 31, hi = lane >> 5;
  const int bid = blockIdx.x;                    // 256 blocks
  const int logical = (bid & 7) * 32 + (bid >> 3);
  const int hb = logical >> 2, qt = logical & 3; // head inst, q-tile(256)
  const int b = hb >> 3, h = hb & 7;
  const int q0 = qt * 256 + wave * 32;
  const size_t base = (size_t)(b * NH + h) * SEQ * DH;
  const char* Kg = (const char*)(Kb + base);
  const char* Vg = (const char*)(Vtb + base);
  const float scale = 0.08838834764831845f * 1.44269504088896340f;

  // Q fragments: lane holds Q[q0+l31][k = kd*16 + hi*8 + j]
  s16x8 qf[8];
  {
    const char* qrow = (const char*)(Qb + base) + (size_t)(q0 + l31) * 256 + hi * 16;
#pragma unroll
    for (int kd = 0; kd < 8; kd++) qf[kd] = *(const s16x8*)(qrow + kd * 32);
  }

  float m_run = -INFINITY, l_run = 0.f;
  f32x16 oacc[4] = {};   // oacc[dt][reg]: q=crow(reg,hi), d=dt*32+l31

  const int v4r = ((((lane & 7) << 1) ^ ((lane >> 3) & 3))) << 4;
  const int v3r = (((lane & 7) ^ ((lane >> 3) & 3))) << 4;

  stage_kv(Kg, Vg, 0, Klds[0], Vtlds[0], tid, wave);

  for (int it = 0; it < 16; ++it) {
    const int cur = it & 1;
    __syncthreads();
    if (it < 15)
      stage_kv(Kg, Vg, (it + 1) * 64, Klds[cur ^ 1], Vtlds[cur ^ 1], tid, wave);

    // ---- QK^T: S^T[k][q], k in [0,64) as two 32-row tiles ----
    f32x16 st0 = {}, st1 = {};
    const char* Kb0 = (const char*)Klds[cur] + l31 * 256;
    __builtin_amdgcn_s_setprio(1);
#pragma unroll
    for (int kd = 0; kd < 8; kd++) {
      int co = (kd * 32 + hi * 16) ^ v4r;
      s16x8 a0 = *(const s16x8*)(Kb0 + co);
      s16x8 a1 = *(const s16x8*)(Kb0 + 32 * 256 + co);
      st0 = mfma32(a0, qf[kd], st0);
      st1 = mfma32(a1, qf[kd], st1);
    }
    __builtin_amdgcn_s_setprio(0);

    // ---- online softmax (exp2 domain, defer-max THR=8) ----
    float traw = -INFINITY;
#pragma unroll
    for (int r = 0; r < 16; r++) {
      traw = fmaxf(traw, st0[r]);
      traw = fmaxf(traw, st1[r]);
    }
    traw = fmaxf(traw, __shfl_xor(traw, 32));
    float tmax = traw * scale;
    const bool skip = __all(tmax - m_run <= 8.f);
    float m_new = skip ? m_run : fmaxf(m_run, tmax);
    float psum = 0.f;
    unsigned W0[8], W1[8];
#pragma unroll
    for (int i = 0; i < 8; i++) {
      float p0 = exp2f(fmaf(st0[2 * i],     scale, -m_new));
      float p1 = exp2f(fmaf(st0[2 * i + 1], scale, -m_new));
      float p2 = exp2f(fmaf(st1[2 * i],     scale, -m_new));
      float p3 = exp2f(fmaf(st1[2 * i + 1], scale, -m_new));
      psum += (p0 + p1) + (p2 + p3);
      W0[i] = pack2bf(p0, p1);
      W1[i] = pack2bf(p2, p3);
    }
    psum += __shfl_xor(psum, 32);
    if (skip) {
      l_run += psum;
    } else {
      float fac = exp2f(m_run - m_new);
      l_run = l_run * fac + psum;
      m_run = m_new;
#pragma unroll
      for (int reg = 0; reg < 16; reg++) {
        int qs = (reg & 3) + 8 * (reg >> 2);
        float fr = __shfl(fac, qs + 4 * hi);
#pragma unroll
        for (int dt = 0; dt < 4; dt++) oacc[dt][reg] *= fr;
      }
    }

    // ---- P -> PV A-fragments: 8 x shfl_xor(32) ----
    s16x8 pa[4];
#pragma unroll
    for (int ks = 0; ks < 4; ks++) {
      const int s4 = (ks & 1) * 4;
      unsigned a0, a1, b0, b1;
      if (ks >> 1) { a0 = W1[s4]; a1 = W1[s4 + 1]; b0 = W1[s4 + 2]; b1 = W1[s4 + 3]; }
      else         { a0 = W0[s4]; a1 = W0[s4 + 1]; b0 = W0[s4 + 2]; b1 = W0[s4 + 3]; }
      unsigned snd0 = hi ? a0 : b0, snd1 = hi ? a1 : b1;
      unsigned rem0 = __shfl_xor(snd0, 32), rem1 = __shfl_xor(snd1, 32);
      unsigned w0 = hi ? rem0 : a0;
      unsigned w1 = hi ? rem1 : a1;
      unsigned w2 = hi ? b0 : rem0;
      unsigned w3 = hi ? b1 : rem1;
      u32x4 t4 = {w0, w1, w2, w3};
      pa[ks] = __builtin_bit_cast(s16x8, t4);
    }

    // ---- PV: oacc[dt] += P(32x64) . V(64x32dt) ----
    const char* Vb0 = (const char*)Vtlds[cur] + l31 * 128;
    __builtin_amdgcn_s_setprio(1);
#pragma unroll
    for (int dt = 0; dt < 4; dt++) {
#pragma unroll
      for (int ks = 0; ks < 4; ks++) {
        int co = (ks * 32 + hi * 16) ^ v3r;
        s16x8 bv = *(const s16x8*)(Vb0 + dt * 4096 + co);
        oacc[dt] = mfma32(pa[ks], bv, oacc[dt]);
      }
    }
    __builtin_amdgcn_s_setprio(0);
  }

  // ---- sentinel column: score = (q . s) * scale, value = s ----
  s16x8 sf[8];
  {
    const char* srow = (const char*)(Sb + base) + (size_t)(q0 + l31) * 256 + hi * 16;
#pragma unroll
    for (int kd = 0; kd < 8; kd++) sf[kd] = *(const s16x8*)(srow + kd * 32);
  }
  float dot = 0.f;
#pragma unroll
  for (int kd = 0; kd < 8; kd++)
#pragma unroll
    for (int j = 0; j < 8; j++) dot += bf2f(qf[kd][j]) * bf2f(sf[kd][j]);
  dot += __shfl_xor(dot, 32);
  float sc = dot * scale;
  float m_new = fmaxf(m_run, sc);
  float fac = exp2f(m_run - m_new);
  float ps = exp2f(sc - m_new);
  l_run = l_run * fac + ps;
  float inv_l = 1.f / l_run;

  // ---- finalize + write ----
#pragma unroll
  for (int reg = 0; reg < 16; reg++) {
    int qs = (reg & 3) + 8 * (reg >> 2) + 4 * hi;
    int qsl = (reg & 3) + 8 * (reg >> 2);
    float fr = __shfl(fac,   qsl + 4 * hi);
    float pr = __shfl(ps,    qsl + 4 * hi);
    float il = __shfl(inv_l, qsl + 4 * hi);
    int qg = q0 + qs;
    const short* Sr = Sb + base + (size_t)qg * DH;
    short* orow = att + ((size_t)b * SEQ + qg) * (NH * DH) + h * DH;
#pragma unroll
    for (int dt = 0; dt < 4; dt++) {
      int d = dt * 32 + l31;
      float v = oacc[dt][reg] * fr + pr * bf2f(Sr[d]);
      orow[d] = bf16r(v * il);
    }
  }
}

extern "C" void kernel_launch(void* const* d_in, const int* in_sizes, int n_in,
                              void* d_out, int out_size, void* d_ws, size_t ws_size,
                              hipStream_t stream) {
  const float* queries = (const float*)d_in[0];
  const float* keys    = (const float*)d_in[1];
  const float* values  = (const float*)d_in[2];
  const float* lang    = (const float*)d_in[3];
  const float* Wq = (const float*)d_in[4];  const float* bq = (const float*)d_in[5];
  const float* Wk = (const float*)d_in[6];  const float* bk = (const float*)d_in[7];
  const float* Wv = (const float*)d_in[8];  const float* bv = (const float*)d_in[9];
  const float* Ws = (const float*)d_in[10]; const float* bs = (const float*)d_in[11];
  const float* Wo = (const float*)d_in[12]; const float* bo = (const float*)d_in[13];
  float* out = (float*)d_out;

  short* ws = (short*)d_ws;
  const size_t NE = (size_t)BATCH * SEQ * DM;      // 8,388,608
  const size_t WE = (size_t)DM * DM;               // 1,048,576
  short* qbf = ws;
  short* kbf = qbf + NE;
  short* vbf = kbf + NE;
  short* sbf = vbf + NE;
  short* Qb  = sbf + NE;
  short* Kb  = Qb  + NE;
  short* Vtb = Kb  + NE;
  short* Sb  = Vtb + NE;
  short* wqb = Sb  + NE;
  short* wkb = wqb + WE;
  short* wvb = wkb + WE;
  short* wsb = wvb + WE;
  short* wob = wsb + WE;
  short* att = qbf;  // alias: qbf dead after proj_gemm

  hipLaunchKernelGGL(cvt_all, dim3(16384 + 2560), dim3(256), 0, stream,
                     queries, keys, values, lang, Wq, Wk, Wv, Ws, Wo,
                     qbf, kbf, vbf, sbf, wqb, wkb, wvb, wsb, wob);

  hipLaunchKernelGGL(proj_gemm, dim3(64, 8, 4), dim3(256), 0, stream,
                     qbf, kbf, vbf, sbf, wqb, wkb, wvb, wsb,
                     bq, bk, bv, bs, Qb, Kb, Vtb, Sb);

  hipLaunchKernelGGL(attn_kernel, dim3(256), dim3(512), 0, stream,
                     Qb, Kb, Vtb, Sb, att);

  hipLaunchKernelGGL(out_gemm, dim3(512), dim3(256), 0, stream,
                     att, wob, bo, out);
}

// Round 15
// 197.438 us; speedup vs baseline: 1.0426x; 1.0426x over previous
//
#include <hip/hip_runtime.h>
#include <hip/hip_bf16.h>

// AdaptiveScaledDotProductAttention (MI355X / gfx950)
// B=8, NQ=NK=1024, D_MODEL=1024, H=8, D_K=D_V=128
// Pipeline: bf16 pre-convert (one kernel) -> fused 4x projection GEMM
// (128x128, BK=64, global_load_lds + XOR-swizzled LDS; V transposed with
// packed 8B stores) -> flash attention with sentinel (32x32x16 MFMA,
// 8 waves x 32 q-rows, 1 barrier/iter, defer-max, setprio, XCD-clustered)
// -> out GEMM (clustered map: A is L3-warm, L2 weight-sharing is profit).
//
// FINAL kernel (best measured: 197.56us; band 197.6-200.0 across r9/r10/r12).
// Session ledger (rounds 1-14): 15 variants tested, 1 win.
//   - 256x256 8-phase counted-vmcnt schedules (x3): MfmaUtil 20-22 vs 30+;
//     1-block/CU lockstep loses to 3-block TLP on this shape.
//   - L2 XCD-clustering of proj blocks (x2): FETCH down but dur +28%
//     (cold-A latency-bound; correlated misses lengthen the vmcnt drain).
//   - fp32-A fused convert: cold-miss exposure inside K-loop, -110%.
//   - 32x32x16 MFMA in GEMM cores: 8.4M LDS bank conflicts, -11%.
//   - attn 2-block split: neutral. out_gemm decorrelated map: -4us.
//   - cvt nt-loads (r14): FETCH unchanged, total +8us -> nt does not
//     improve L3 retention here; reverted.
// WIN (r9, confirmed r10/r12): V^T epilogue packs 4 sq-consecutive acc
// elements into one short4 8B store (was 4x 2B scatter at 2KB stride):
// WRITE 85->66MB, FETCH 77->65.7MB (RMW read-for-ownership eliminated),
// 215.4 -> 197.6us.

typedef __attribute__((ext_vector_type(8))) short s16x8;
typedef __attribute__((ext_vector_type(4))) short s16x4;
typedef __attribute__((ext_vector_type(4))) float f32x4;
typedef __attribute__((ext_vector_type(16))) float f32x16;
typedef __attribute__((ext_vector_type(4))) unsigned int u32x4;

#define DEVI static __device__ __forceinline__

constexpr int BATCH = 8;
constexpr int SEQ   = 1024;
constexpr int NH    = 8;
constexpr int DH    = 128;
constexpr int DM    = 1024;

DEVI short bf16r(float f) {
  __hip_bfloat16 h = __float2bfloat16(f);
  return *reinterpret_cast<short*>(&h);
}
DEVI float bf2f(short s) {
  __hip_bfloat16 h;
  *reinterpret_cast<short*>(&h) = s;
  return __bfloat162float(h);
}
DEVI s16x8 cvt8(const float4& a, const float4& b) {
  s16x8 r;
  r[0] = bf16r(a.x); r[1] = bf16r(a.y); r[2] = bf16r(a.z); r[3] = bf16r(a.w);
  r[4] = bf16r(b.x); r[5] = bf16r(b.y); r[6] = bf16r(b.z); r[7] = bf16r(b.w);
  return r;
}
DEVI unsigned int pack2bf(float a, float b) {
  return (unsigned int)(unsigned short)bf16r(a) |
         ((unsigned int)(unsigned short)bf16r(b) << 16);
}

#define GLOAD16(g, l)                                                        \
  __builtin_amdgcn_global_load_lds(                                          \
      (const __attribute__((address_space(1))) unsigned int*)(g),            \
      (__attribute__((address_space(3))) unsigned int*)(l), 16, 0, 0)

DEVI f32x4 mfma(s16x8 a, s16x8 b, f32x4 c) {
  return __builtin_amdgcn_mfma_f32_16x16x32_bf16(a, b, c, 0, 0, 0);
}
DEVI f32x16 mfma32(s16x8 a, s16x8 b, f32x16 c) {
  return __builtin_amdgcn_mfma_f32_32x32x16_bf16(a, b, c, 0, 0, 0);
}

// ---------------- fp32 -> bf16 convert, all 9 tensors, one launch ----------
__global__ __launch_bounds__(256)
void cvt_all(const float* __restrict__ a0, const float* __restrict__ a1,
             const float* __restrict__ a2, const float* __restrict__ a3,
             const float* __restrict__ w0, const float* __restrict__ w1,
             const float* __restrict__ w2, const float* __restrict__ w3,
             const float* __restrict__ w4,
             short* __restrict__ d0, short* __restrict__ d1,
             short* __restrict__ d2, short* __restrict__ d3,
             short* __restrict__ e0, short* __restrict__ e1,
             short* __restrict__ e2, short* __restrict__ e3,
             short* __restrict__ e4) {
  const float* s; short* d; int idx;
  int bid = blockIdx.x;
  if (bid < 16384) {
    int which = bid >> 12; idx = bid & 4095;
    switch (which) {
      case 0: s = a0; d = d0; break;
      case 1: s = a1; d = d1; break;
      case 2: s = a2; d = d2; break;
      default: s = a3; d = d3; break;
    }
  } else {
    int r = bid - 16384;
    int which = r >> 9; idx = r & 511;
    switch (which) {
      case 0: s = w0; d = e0; break;
      case 1: s = w1; d = e1; break;
      case 2: s = w2; d = e2; break;
      case 3: s = w3; d = e3; break;
      default: s = w4; d = e4; break;
    }
  }
  size_t i = ((size_t)idx * 256 + threadIdx.x) * 8;
  float4 a = *(const float4*)(s + i);
  float4 b = *(const float4*)(s + i + 4);
  *(s16x8*)(d + i) = cvt8(a, b);
}

// ---------------- GEMM core (128x128 tile, BK=64, swizzled LDS) ------------
DEVI void gemm_core(const short* __restrict__ A, const short* __restrict__ W,
                    short* Alds, short* Blds, int m0, int n0,
                    f32x4 (&acc)[4][4]) {
  const int tid = threadIdx.x, lane = tid & 63, wid = tid >> 6;
  const int wm = wid >> 1, wn = wid & 1, lr = lane & 15, lg = lane >> 4;
  const int srow = wid * 32 + (lane >> 3);
  const int scb  = (lane & 7) * 16;

  for (int k0 = 0; k0 < DM; k0 += 64) {
    if (k0) __syncthreads();
#pragma unroll
    for (int t = 0; t < 4; t++) {
      int row = srow + t * 8;
      int cbs = scb ^ ((row & 7) << 4);
      GLOAD16((const char*)A + ((size_t)(m0 + row) * DM + k0) * 2 + cbs,
              (char*)Alds + wid * 4096 + t * 1024);
      GLOAD16((const char*)W + ((size_t)(n0 + row) * DM + k0) * 2 + cbs,
              (char*)Blds + wid * 4096 + t * 1024);
    }
    __syncthreads();
#pragma unroll
    for (int kk = 0; kk < 2; kk++) {
      s16x8 af[4], bf[4];
#pragma unroll
      for (int i = 0; i < 4; i++) {
        int row = wm * 64 + i * 16 + lr;
        af[i] = *(const s16x8*)((const char*)Alds + row * 128 +
                                ((kk * 64 + lg * 16) ^ ((row & 7) << 4)));
      }
#pragma unroll
      for (int j = 0; j < 4; j++) {
        int row = wn * 64 + j * 16 + lr;
        bf[j] = *(const s16x8*)((const char*)Blds + row * 128 +
                                ((kk * 64 + lg * 16) ^ ((row & 7) << 4)));
      }
#pragma unroll
      for (int i = 0; i < 4; i++)
#pragma unroll
        for (int j = 0; j < 4; j++)
          acc[i][j] = mfma(af[i], bf[j], acc[i][j]);
    }
  }
}

// Fused 4-way projection GEMM. z: 0=Q 1=K 2=V(writes V^T) 3=S
__global__ __launch_bounds__(256)
void proj_gemm(const short* __restrict__ qa, const short* __restrict__ ka,
               const short* __restrict__ va, const short* __restrict__ sa,
               const short* __restrict__ wq, const short* __restrict__ wk,
               const short* __restrict__ wv, const short* __restrict__ wsn,
               const float* __restrict__ bq, const float* __restrict__ bk,
               const float* __restrict__ bv, const float* __restrict__ bsn,
               short* __restrict__ Qo, short* __restrict__ Ko,
               short* __restrict__ Vo, short* __restrict__ So) {
  __shared__ short Alds[128 * 64];
  __shared__ short Blds[128 * 64];
  const int z = blockIdx.z;
  const short* A; const short* W; const float* bias; short* C;
  switch (z) {
    case 0: A = qa; W = wq;  bias = bq;  C = Qo; break;
    case 1: A = ka; W = wk;  bias = bk;  C = Ko; break;
    case 2: A = va; W = wv;  bias = bv;  C = Vo; break;
    default: A = sa; W = wsn; bias = bsn; C = So; break;
  }
  const int m0 = blockIdx.x * 128, n0 = blockIdx.y * 128;
  f32x4 acc[4][4] = {};
  gemm_core(A, W, Alds, Blds, m0, n0, acc);

  const int lane = threadIdx.x & 63, wid = threadIdx.x >> 6;
  const int wm = wid >> 1, wn = wid & 1, lr = lane & 15, lg = lane >> 4;
  if (z == 2) {
    // V^T: acc[i][j][0..3] are sq-consecutive -> one 8B packed store each
    // (was 4x 2B at 2KB stride; removes partial-line RMW amplification).
#pragma unroll
    for (int i = 0; i < 4; i++) {
      int mb = m0 + wm * 64 + i * 16 + lg * 4;   // r=0 row
      int bb = mb >> 10, sqb = mb & 1023;        // sqb multiple of 4 -> 8B aligned
#pragma unroll
      for (int j = 0; j < 4; j++) {
        int n = n0 + wn * 64 + j * 16 + lr;
        int hh = n >> 7, d = n & 127;
        float bsv = bias[n];
        s16x4 pk;
#pragma unroll
        for (int r = 0; r < 4; r++) pk[r] = bf16r(acc[i][j][r] + bsv);
        *(s16x4*)(&C[((size_t)(bb * NH + hh) * DH + d) * SEQ + sqb]) = pk;
      }
    }
  } else {
#pragma unroll
    for (int i = 0; i < 4; i++) {
#pragma unroll
      for (int r = 0; r < 4; r++) {
        int m = m0 + wm * 64 + i * 16 + lg * 4 + r;
        int bb = m >> 10, sq = m & 1023;
#pragma unroll
        for (int j = 0; j < 4; j++) {
          int n = n0 + wn * 64 + j * 16 + lr;
          float v = acc[i][j][r] + bias[n];
          int hh = n >> 7, d = n & 127;
          C[((size_t)(bb * NH + hh) * SEQ + sq) * DH + d] = bf16r(v);
        }
      }
    }
  }
}

// Output GEMM: att(bf16 [8192][1024]) @ Wo^T + bo -> fp32 [8192][1024]
// Clustered map kept: A (att) is L3-warm so L2 weight-sharing is pure
// profit here (r11 decorrelation experiment: -4us).
__global__ __launch_bounds__(256)
void out_gemm(const short* __restrict__ A, const short* __restrict__ W,
              const float* __restrict__ bias, float* __restrict__ C) {
  __shared__ short Alds[128 * 64];
  __shared__ short Blds[128 * 64];
  const int bid = blockIdx.x;
  const int wg = (bid & 7) * 64 + (bid >> 3);
  const int m0 = (wg >> 3) * 128, n0 = (wg & 7) * 128;
  f32x4 acc[4][4] = {};
  gemm_core(A, W, Alds, Blds, m0, n0, acc);

  const int lane = threadIdx.x & 63, wid = threadIdx.x >> 6;
  const int wm = wid >> 1, wn = wid & 1, lr = lane & 15, lg = lane >> 4;
#pragma unroll
  for (int i = 0; i < 4; i++)
#pragma unroll
    for (int r = 0; r < 4; r++) {
      int m = m0 + wm * 64 + i * 16 + lg * 4 + r;
#pragma unroll
      for (int j = 0; j < 4; j++) {
        int n = n0 + wn * 64 + j * 16 + lr;
        C[(size_t)m * DM + n] = acc[i][j][r] + bias[n];
      }
    }
}

// ---------------- flash attention with sentinel (32x32x16 MFMA) ------------
// Q,K,S: bf16 [b][h][seq][128]; Vt: bf16 [b][h][128][seq]; att: [b][seq][h*128]
// 8 waves x 32 q-rows = 256 q/block sharing one 64KB K/V double-buffer.
DEVI void stage_kv(const char* Kg, const char* Vg, int k0n,
                   short* Kd, short* Vd, int tid, int wave) {
  const int krow_l = tid >> 4, kslot = tid & 15;   // 512 thr: rows 0..31
  const int vrow_l = tid >> 3, vslot = tid & 7;    // rows 0..63
#pragma unroll
  for (int ln = 0; ln < 2; ln++) {
    int kr = ln * 32 + krow_l;
    int ss = kslot ^ (((kr & 7) << 1) ^ ((kr >> 3) & 3));
    GLOAD16(Kg + (size_t)(k0n + kr) * 256 + ss * 16,
            (char*)Kd + ln * 8192 + wave * 1024);
  }
#pragma unroll
  for (int ln = 0; ln < 2; ln++) {
    int dr = ln * 64 + vrow_l;
    int ss = vslot ^ ((dr & 7) ^ ((dr >> 3) & 3));
    GLOAD16(Vg + (size_t)dr * 2048 + (size_t)k0n * 2 + ss * 16,
            (char*)Vd + ln * 8192 + wave * 1024);
  }
}

__global__ __launch_bounds__(512, 2)
void attn_kernel(const short* __restrict__ Qb, const short* __restrict__ Kb,
                 const short* __restrict__ Vtb, const short* __restrict__ Sb,
                 short* __restrict__ att) {
  __shared__ short Klds[2][64 * 128];    // [k][128], 256B rows, 2x16KB
  __shared__ short Vtlds[2][128 * 64];   // [d][64], 128B rows, 2x16KB

  const int tid = threadIdx.x, lane = tid & 63, wave = tid >> 6;  // 0..7
  const int l31 = lane & 31, hi = lane >> 5;
  const int bid = blockIdx.x;                    // 256 blocks
  const int logical = (bid & 7) * 32 + (bid >> 3);
  const int hb = logical >> 2, qt = logical & 3; // head inst, q-tile(256)
  const int b = hb >> 3, h = hb & 7;
  const int q0 = qt * 256 + wave * 32;
  const size_t base = (size_t)(b * NH + h) * SEQ * DH;
  const char* Kg = (const char*)(Kb + base);
  const char* Vg = (const char*)(Vtb + base);
  const float scale = 0.08838834764831845f * 1.44269504088896340f;

  // Q fragments: lane holds Q[q0+l31][k = kd*16 + hi*8 + j]
  s16x8 qf[8];
  {
    const char* qrow = (const char*)(Qb + base) + (size_t)(q0 + l31) * 256 + hi * 16;
#pragma unroll
    for (int kd = 0; kd < 8; kd++) qf[kd] = *(const s16x8*)(qrow + kd * 32);
  }

  float m_run = -INFINITY, l_run = 0.f;
  f32x16 oacc[4] = {};   // oacc[dt][reg]: q=crow(reg,hi), d=dt*32+l31

  const int v4r = ((((lane & 7) << 1) ^ ((lane >> 3) & 3))) << 4;
  const int v3r = (((lane & 7) ^ ((lane >> 3) & 3))) << 4;

  stage_kv(Kg, Vg, 0, Klds[0], Vtlds[0], tid, wave);

  for (int it = 0; it < 16; ++it) {
    const int cur = it & 1;
    __syncthreads();
    if (it < 15)
      stage_kv(Kg, Vg, (it + 1) * 64, Klds[cur ^ 1], Vtlds[cur ^ 1], tid, wave);

    // ---- QK^T: S^T[k][q], k in [0,64) as two 32-row tiles ----
    f32x16 st0 = {}, st1 = {};
    const char* Kb0 = (const char*)Klds[cur] + l31 * 256;
    __builtin_amdgcn_s_setprio(1);
#pragma unroll
    for (int kd = 0; kd < 8; kd++) {
      int co = (kd * 32 + hi * 16) ^ v4r;
      s16x8 a0 = *(const s16x8*)(Kb0 + co);
      s16x8 a1 = *(const s16x8*)(Kb0 + 32 * 256 + co);
      st0 = mfma32(a0, qf[kd], st0);
      st1 = mfma32(a1, qf[kd], st1);
    }
    __builtin_amdgcn_s_setprio(0);

    // ---- online softmax (exp2 domain, defer-max THR=8) ----
    float traw = -INFINITY;
#pragma unroll
    for (int r = 0; r < 16; r++) {
      traw = fmaxf(traw, st0[r]);
      traw = fmaxf(traw, st1[r]);
    }
    traw = fmaxf(traw, __shfl_xor(traw, 32));
    float tmax = traw * scale;
    const bool skip = __all(tmax - m_run <= 8.f);
    float m_new = skip ? m_run : fmaxf(m_run, tmax);
    float psum = 0.f;
    unsigned W0[8], W1[8];
#pragma unroll
    for (int i = 0; i < 8; i++) {
      float p0 = exp2f(fmaf(st0[2 * i],     scale, -m_new));
      float p1 = exp2f(fmaf(st0[2 * i + 1], scale, -m_new));
      float p2 = exp2f(fmaf(st1[2 * i],     scale, -m_new));
      float p3 = exp2f(fmaf(st1[2 * i + 1], scale, -m_new));
      psum += (p0 + p1) + (p2 + p3);
      W0[i] = pack2bf(p0, p1);
      W1[i] = pack2bf(p2, p3);
    }
    psum += __shfl_xor(psum, 32);
    if (skip) {
      l_run += psum;
    } else {
      float fac = exp2f(m_run - m_new);
      l_run = l_run * fac + psum;
      m_run = m_new;
#pragma unroll
      for (int reg = 0; reg < 16; reg++) {
        int qs = (reg & 3) + 8 * (reg >> 2);
        float fr = __shfl(fac, qs + 4 * hi);
#pragma unroll
        for (int dt = 0; dt < 4; dt++) oacc[dt][reg] *= fr;
      }
    }

    // ---- P -> PV A-fragments: 8 x shfl_xor(32) ----
    s16x8 pa[4];
#pragma unroll
    for (int ks = 0; ks < 4; ks++) {
      const int s4 = (ks & 1) * 4;
      unsigned a0, a1, b0, b1;
      if (ks >> 1) { a0 = W1[s4]; a1 = W1[s4 + 1]; b0 = W1[s4 + 2]; b1 = W1[s4 + 3]; }
      else         { a0 = W0[s4]; a1 = W0[s4 + 1]; b0 = W0[s4 + 2]; b1 = W0[s4 + 3]; }
      unsigned snd0 = hi ? a0 : b0, snd1 = hi ? a1 : b1;
      unsigned rem0 = __shfl_xor(snd0, 32), rem1 = __shfl_xor(snd1, 32);
      unsigned w0 = hi ? rem0 : a0;
      unsigned w1 = hi ? rem1 : a1;
      unsigned w2 = hi ? b0 : rem0;
      unsigned w3 = hi ? b1 : rem1;
      u32x4 t4 = {w0, w1, w2, w3};
      pa[ks] = __builtin_bit_cast(s16x8, t4);
    }

    // ---- PV: oacc[dt] += P(32x64) . V(64x32dt) ----
    const char* Vb0 = (const char*)Vtlds[cur] + l31 * 128;
    __builtin_amdgcn_s_setprio(1);
#pragma unroll
    for (int dt = 0; dt < 4; dt++) {
#pragma unroll
      for (int ks = 0; ks < 4; ks++) {
        int co = (ks * 32 + hi * 16) ^ v3r;
        s16x8 bv = *(const s16x8*)(Vb0 + dt * 4096 + co);
        oacc[dt] = mfma32(pa[ks], bv, oacc[dt]);
      }
    }
    __builtin_amdgcn_s_setprio(0);
  }

  // ---- sentinel column: score = (q . s) * scale, value = s ----
  s16x8 sf[8];
  {
    const char* srow = (const char*)(Sb + base) + (size_t)(q0 + l31) * 256 + hi * 16;
#pragma unroll
    for (int kd = 0; kd < 8; kd++) sf[kd] = *(const s16x8*)(srow + kd * 32);
  }
  float dot = 0.f;
#pragma unroll
  for (int kd = 0; kd < 8; kd++)
#pragma unroll
    for (int j = 0; j < 8; j++) dot += bf2f(qf[kd][j]) * bf2f(sf[kd][j]);
  dot += __shfl_xor(dot, 32);
  float sc = dot * scale;
  float m_new = fmaxf(m_run, sc);
  float fac = exp2f(m_run - m_new);
  float ps = exp2f(sc - m_new);
  l_run = l_run * fac + ps;
  float inv_l = 1.f / l_run;

  // ---- finalize + write ----
#pragma unroll
  for (int reg = 0; reg < 16; reg++) {
    int qs = (reg & 3) + 8 * (reg >> 2) + 4 * hi;
    int qsl = (reg & 3) + 8 * (reg >> 2);
    float fr = __shfl(fac,   qsl + 4 * hi);
    float pr = __shfl(ps,    qsl + 4 * hi);
    float il = __shfl(inv_l, qsl + 4 * hi);
    int qg = q0 + qs;
    const short* Sr = Sb + base + (size_t)qg * DH;
    short* orow = att + ((size_t)b * SEQ + qg) * (NH * DH) + h * DH;
#pragma unroll
    for (int dt = 0; dt < 4; dt++) {
      int d = dt * 32 + l31;
      float v = oacc[dt][reg] * fr + pr * bf2f(Sr[d]);
      orow[d] = bf16r(v * il);
    }
  }
}

extern "C" void kernel_launch(void* const* d_in, const int* in_sizes, int n_in,
                              void* d_out, int out_size, void* d_ws, size_t ws_size,
                              hipStream_t stream) {
  const float* queries = (const float*)d_in[0];
  const float* keys    = (const float*)d_in[1];
  const float* values  = (const float*)d_in[2];
  const float* lang    = (const float*)d_in[3];
  const float* Wq = (const float*)d_in[4];  const float* bq = (const float*)d_in[5];
  const float* Wk = (const float*)d_in[6];  const float* bk = (const float*)d_in[7];
  const float* Wv = (const float*)d_in[8];  const float* bv = (const float*)d_in[9];
  const float* Ws = (const float*)d_in[10]; const float* bs = (const float*)d_in[11];
  const float* Wo = (const float*)d_in[12]; const float* bo = (const float*)d_in[13];
  float* out = (float*)d_out;

  short* ws = (short*)d_ws;
  const size_t NE = (size_t)BATCH * SEQ * DM;      // 8,388,608
  const size_t WE = (size_t)DM * DM;               // 1,048,576
  short* qbf = ws;
  short* kbf = qbf + NE;
  short* vbf = kbf + NE;
  short* sbf = vbf + NE;
  short* Qb  = sbf + NE;
  short* Kb  = Qb  + NE;
  short* Vtb = Kb  + NE;
  short* Sb  = Vtb + NE;
  short* wqb = Sb  + NE;
  short* wkb = wqb + WE;
  short* wvb = wkb + WE;
  short* wsb = wvb + WE;
  short* wob = wsb + WE;
  short* att = qbf;  // alias: qbf dead after proj_gemm

  hipLaunchKernelGGL(cvt_all, dim3(16384 + 2560), dim3(256), 0, stream,
                     queries, keys, values, lang, Wq, Wk, Wv, Ws, Wo,
                     qbf, kbf, vbf, sbf, wqb, wkb, wvb, wsb, wob);

  hipLaunchKernelGGL(proj_gemm, dim3(64, 8, 4), dim3(256), 0, stream,
                     qbf, kbf, vbf, sbf, wqb, wkb, wvb, wsb,
                     bq, bk, bv, bs, Qb, Kb, Vtb, Sb);

  hipLaunchKernelGGL(attn_kernel, dim3(256), dim3(512), 0, stream,
                     Qb, Kb, Vtb, Sb, att);

  hipLaunchKernelGGL(out_gemm, dim3(512), dim3(256), 0, stream,
                     att, wob, bo, out);
}